// Round 6
// baseline (423.598 us; speedup 1.0000x reference)
//
#include <hip/hip_runtime.h>
#include <stdint.h>

typedef __bf16 bf16;
typedef __attribute__((ext_vector_type(8))) __bf16 bf16x8;
typedef __attribute__((ext_vector_type(4))) __bf16 bf16x4;
typedef __attribute__((ext_vector_type(4))) short short4v;
typedef __attribute__((ext_vector_type(4))) float f32x4;

static constexpr int Bn = 2, Ln = 2048, DIMn = 2048, Hn = 32, KVn = 8, HDn = 64;
static constexpr int TS = 3072;  // fused qkv token stride (2048 q + 512 k + 512 v)

#if defined(__has_builtin)
#if __has_builtin(__builtin_amdgcn_exp2f)
#define EXP2(x) __builtin_amdgcn_exp2f(x)
#endif
#endif
#ifndef EXP2
#define EXP2(x) exp2f(x)
#endif

#define TO_LDS(p) ((__attribute__((address_space(3))) uint32_t*)(uintptr_t)(p))
#define TO_GLB(p) ((const __attribute__((address_space(1))) uint32_t*)(uintptr_t)(p))

// ---------------- fused cast fp32 -> bf16 for all 5 inputs ----------------
__global__ void cast_all(const float* __restrict__ x, const float* __restrict__ wq,
                         const float* __restrict__ wk, const float* __restrict__ wv,
                         const float* __restrict__ wo, bf16* __restrict__ xb,
                         bf16* __restrict__ wqkvb, bf16* __restrict__ wob) {
    size_t i = (size_t)(blockIdx.x * blockDim.x + threadIdx.x) * 4;
    const float* src;
    bf16* dst;
    if (i < 8388608) {
        src = x + i; dst = xb + i;
    } else if (i < 8388608 + 6291456) {
        size_t j = i - 8388608;
        dst = wqkvb + j;
        if (j < 4194304)      src = wq + j;
        else if (j < 5242880) src = wk + (j - 4194304);
        else                  src = wv + (j - 5242880);
    } else {
        size_t j = i - 14680064;
        src = wo + j; dst = wob + j;
    }
    float4 v = *(const float4*)src;
    bf16 o[4] = {(bf16)v.x, (bf16)v.y, (bf16)v.z, (bf16)v.w};
    *(uint64_t*)dst = *(uint64_t*)o;
}

// ---------------- RoPE in-place on K region of qkv (cols 2048..2559) ----------------
__global__ void rope_k(bf16* __restrict__ qkv, const float* __restrict__ fc) {
    int idx = blockIdx.x * blockDim.x + threadIdx.x;   // T * 8 * 32 = 1,048,576
    int i   = idx & 31;
    int kvh = (idx >> 5) & 7;
    int bl  = idx >> 8;
    int l   = bl & (Ln - 1);
    size_t base = (size_t)bl * TS + 2048 + kvh * 64 + 2 * i;
    float cr = fc[l * 32 + i];
    float sr = fc[65536 + l * 32 + i];
    float x0 = (float)qkv[base], x1 = (float)qkv[base + 1];
    qkv[base]     = (bf16)(x0 * cr - x1 * sr);
    qkv[base + 1] = (bf16)(x0 * sr + x1 * cr);
}

// ---------------- transpose V region -> Vt[b][kvh][hd 64][L 2048] ----------------
__global__ __launch_bounds__(256) void transpose_v(const bf16* __restrict__ qkv,
                                                   bf16* __restrict__ Vt) {
    __shared__ bf16 sT[64][72];
    const int t = threadIdx.x;
    const int lt = blockIdx.x, kvh = blockIdx.y, b = blockIdx.z;
    const bf16* vp = qkv + (size_t)(b * Ln + lt * 64) * TS + 2560 + kvh * 64;
    // stage: thread -> key=t&63, hd0=(t>>6)*16
    {
        int key = t & 63, hd0 = (t >> 6) * 16;
        *(bf16x8*)(&sT[key][hd0])     = *(const bf16x8*)(vp + (size_t)key * TS + hd0);
        *(bf16x8*)(&sT[key][hd0 + 8]) = *(const bf16x8*)(vp + (size_t)key * TS + hd0 + 8);
    }
    __syncthreads();
    // write transposed: thread -> hd=t>>2, kcol=(t&3)*16
    {
        int hd = t >> 2, kcol = (t & 3) * 16;
        bf16 v[16];
#pragma unroll
        for (int j = 0; j < 16; ++j) v[j] = sT[kcol + j][hd];
        bf16* dst = Vt + ((size_t)(b * KVn + kvh) * 64 + hd) * Ln + lt * 64 + kcol;
        *(bf16x8*)(dst)     = *(bf16x8*)(v);
        *(bf16x8*)(dst + 8) = *(bf16x8*)(v + 8);
    }
}

// ---------------- GEMM: C[M,N] = A[M,K] * B[N,K]^T  (bf16 in, fp32 acc) ----------------
template <bool OUT_BF16>
__global__ __launch_bounds__(256) void gemm_bt(const bf16* __restrict__ A,
                                               const bf16* __restrict__ Bm,
                                               void* __restrict__ C,
                                               int M, int N, int K) {
    __shared__ bf16 sA[128 * 32];
    __shared__ bf16 sB[128 * 32];
    const int t    = threadIdx.x;
    const int wave = t >> 6, lane = t & 63;
    const int q4 = lane >> 4, l16 = lane & 15;
    const int bm = blockIdx.y * 128, bn = blockIdx.x * 128;
    const int wm = (wave >> 1) * 64, wn = (wave & 1) * 64;

    f32x4 acc[4][4] = {};

    const int srow = wave * 16 + (lane >> 2);
    const int scol = (lane & 3) * 8;
    const bf16* pa = A + (size_t)(bm + srow) * K + scol;
    const bf16* pb = Bm + (size_t)(bn + srow) * K + scol;
    bf16* la = &sA[wave * 16 * 32];
    bf16* lb = &sB[wave * 16 * 32];

    for (int k0 = 0; k0 < K; k0 += 32) {
#pragma unroll
        for (int p = 0; p < 2; ++p) {
            __builtin_amdgcn_global_load_lds(TO_GLB(pa + (size_t)p * 64 * K),
                                             TO_LDS(la + p * 64 * 32), 16, 0, 0);
            __builtin_amdgcn_global_load_lds(TO_GLB(pb + (size_t)p * 64 * K),
                                             TO_LDS(lb + p * 64 * 32), 16, 0, 0);
        }
        pa += 32; pb += 32;
        __syncthreads();
        bf16x8 af[4], bfr[4];
#pragma unroll
        for (int i = 0; i < 4; ++i) {
            af[i]  = *(const bf16x8*)(&sA[(wm + i * 16 + l16) * 32 + q4 * 8]);
            bfr[i] = *(const bf16x8*)(&sB[(wn + i * 16 + l16) * 32 + q4 * 8]);
        }
#pragma unroll
        for (int mi = 0; mi < 4; ++mi)
#pragma unroll
            for (int ni = 0; ni < 4; ++ni)
                acc[mi][ni] = __builtin_amdgcn_mfma_f32_16x16x32_bf16(af[mi], bfr[ni],
                                                                      acc[mi][ni], 0, 0, 0);
        __syncthreads();
    }

#pragma unroll
    for (int mi = 0; mi < 4; ++mi)
#pragma unroll
        for (int ni = 0; ni < 4; ++ni)
#pragma unroll
            for (int r = 0; r < 4; ++r) {
                size_t row = bm + wm + mi * 16 + q4 * 4 + r;
                size_t col = bn + wn + ni * 16 + l16;
                if (OUT_BF16)
                    ((bf16*)C)[row * N + col] = (bf16)acc[mi][ni][r];
                else
                    ((float*)C)[row * N + col] = acc[mi][ni][r];
            }
}

// ---------------- flash attention: barrier-free, one wave per (b,h,q-tile) ----------------
// 64-thread blocks, grid (128=4hidx*32qt, KV, B). No LDS, no __syncthreads.
// K fragments loaded directly from global (row-major, pre-roped); V fragments from
// pre-transposed Vt[b][kvh][hd][L]. kf prefetched one tile ahead; vf issued at
// tile-top, consumed after QK+softmax (self-hiding). Static-max softmax in log2
// domain (scale*log2e folded into Q in-register RoPE): p = exp2(s-12), l deferred.
__global__ __launch_bounds__(64, 2) void attn_kernel(const bf16* __restrict__ QKV,
                                                     const bf16* __restrict__ Vt,
                                                     const float* __restrict__ fc,
                                                     bf16* __restrict__ O) {
    const int lane = threadIdx.x;
    const int q4 = lane >> 4, l16 = lane & 15;
    const int qt   = 31 - (blockIdx.x & 31);       // heavy q-tiles first
    const int hidx = blockIdx.x >> 5;              // 0..3
    const int kvh = blockIdx.y, b = blockIdx.z;
    const int h = kvh * 4 + hidx;
    constexpr float SC = 0.125f * 1.44269504088896340736f;

    // ---- load Q fragments, RoPE + scale in-register ----
    bf16x8 qf[4][2];
#pragma unroll
    for (int g = 0; g < 4; ++g) {
        int ql = qt * 64 + g * 16 + l16;
        const bf16* qp = QKV + (size_t)(b * Ln + ql) * TS + h * 64;
#pragma unroll
        for (int hc = 0; hc < 2; ++hc) {
            bf16x8 raw = *(const bf16x8*)(qp + hc * 32 + q4 * 8);
            float4 c4 = *(const float4*)(fc + ql * 32 + hc * 16 + q4 * 4);
            float4 s4 = *(const float4*)(fc + 65536 + ql * 32 + hc * 16 + q4 * 4);
            bf16x8 o;
#pragma unroll
            for (int m = 0; m < 4; ++m) {
                float cr = ((const float*)&c4)[m], sr = ((const float*)&s4)[m];
                float x0 = (float)raw[2 * m], x1 = (float)raw[2 * m + 1];
                o[2 * m]     = (bf16)((x0 * cr - x1 * sr) * SC);
                o[2 * m + 1] = (bf16)((x0 * sr + x1 * cr) * SC);
            }
            qf[g][hc] = o;
        }
    }

    const bf16* kb = QKV + (size_t)(b * Ln) * TS + 2048 + kvh * 64;
    const bf16* vt = Vt + (size_t)(b * KVn + kvh) * 64 * Ln;

    f32x4 o_acc[4][4] = {};
    float l_r[4] = {0.f, 0.f, 0.f, 0.f};

    // kf: A-operand of QK^T, row=c*16+l16 of current key tile
    bf16x8 kf[4][2];
#pragma unroll
    for (int c = 0; c < 4; ++c)
#pragma unroll
        for (int hc = 0; hc < 2; ++hc)
            kf[c][hc] = *(const bf16x8*)(kb + (size_t)(c * 16 + l16) * TS + hc * 32 + q4 * 8);

    for (int kt = 0; kt <= qt; ++kt) {
        // vf: A-operand of PV (V^T), issued now, used after QK+softmax
        short4v vf[4][4];
#pragma unroll
        for (int nc = 0; nc < 4; ++nc)
#pragma unroll
            for (int c = 0; c < 4; ++c)
                vf[nc][c] = *(const short4v*)(vt + (size_t)(nc * 16 + l16) * Ln +
                                              kt * 64 + c * 16 + q4 * 4);

        const bool diag = (kt == qt);
#pragma unroll
        for (int g = 0; g < 4; ++g) {
            f32x4 s[4];
#pragma unroll
            for (int c = 0; c < 4; ++c) {
                f32x4 a = {};
                a = __builtin_amdgcn_mfma_f32_16x16x32_bf16(kf[c][0], qf[g][0], a, 0, 0, 0);
                a = __builtin_amdgcn_mfma_f32_16x16x32_bf16(kf[c][1], qf[g][1], a, 0, 0, 0);
                s[c] = a;
            }
            int qrow = qt * 64 + g * 16 + l16;
            float lsum = 0.f;
            short4v pb4[4];
#pragma unroll
            for (int c = 0; c < 4; ++c)
#pragma unroll
                for (int r = 0; r < 4; ++r) {
                    float p = EXP2(s[c][r] - 12.f);
                    if (diag && (kt * 64 + c * 16 + q4 * 4 + r > qrow)) p = 0.f;
                    lsum += p;
                    bf16 ph = (bf16)p;
                    pb4[c][r] = *(const short*)&ph;
                }
            l_r[g] += lsum;
#pragma unroll
            for (int nc = 0; nc < 4; ++nc)
#pragma unroll
                for (int c = 0; c < 4; ++c)
                    o_acc[g][nc] = __builtin_amdgcn_mfma_f32_16x16x16bf16_1k(
                        vf[nc][c], pb4[c], o_acc[g][nc], 0, 0, 0);
        }

        // prefetch kf for next tile (used first next iteration)
        if (kt < qt) {
            const bf16* kp = kb + (size_t)(kt + 1) * 64 * TS;
#pragma unroll
            for (int c = 0; c < 4; ++c)
#pragma unroll
                for (int hc = 0; hc < 2; ++hc)
                    kf[c][hc] = *(const bf16x8*)(kp + (size_t)(c * 16 + l16) * TS +
                                                 hc * 32 + q4 * 8);
        }
    }

    // ---- epilogue: reduce l across q4 sub-lanes, normalize, store ----
#pragma unroll
    for (int g = 0; g < 4; ++g) {
        float l = l_r[g];
        l += __shfl_xor(l, 16, 64);
        l += __shfl_xor(l, 32, 64);
        float inv = 1.f / l;
        int qrow = qt * 64 + g * 16 + l16;
        bf16* op = O + (size_t)(b * Ln + qrow) * (Hn * HDn) + h * 64;
#pragma unroll
        for (int nc = 0; nc < 4; ++nc) {
            bf16x4 o;
#pragma unroll
            for (int r = 0; r < 4; ++r) o[r] = (bf16)(o_acc[g][nc][r] * inv);
            *(bf16x4*)(op + nc * 16 + q4 * 4) = o;
        }
    }
}

// ---------------- launch ----------------
extern "C" void kernel_launch(void* const* d_in, const int* in_sizes, int n_in,
                              void* d_out, int out_size, void* d_ws, size_t ws_size,
                              hipStream_t stream) {
    const float* x  = (const float*)d_in[0];
    const float* fc = (const float*)d_in[1];
    const float* wq = (const float*)d_in[2];
    const float* wk = (const float*)d_in[3];
    const float* wv = (const float*)d_in[4];
    const float* wo = (const float*)d_in[5];
    float* out = (float*)d_out;

    const size_t T = (size_t)Bn * Ln;  // 4096 tokens
    char* p = (char*)d_ws;
    bf16* xb    = (bf16*)p; p += T * DIMn * 2;
    bf16* wqkvb = (bf16*)p; p += (size_t)TS * DIMn * 2;
    bf16* wob   = (bf16*)p; p += (size_t)DIMn * Hn * HDn * 2;
    bf16* qkv   = (bf16*)p; p += T * TS * 2;
    bf16* ao    = (bf16*)p; p += T * Hn * HDn * 2;
    bf16* vtb   = (bf16*)p; p += (size_t)Bn * KVn * 64 * Ln * 2;

    cast_all<<<dim3(18432), dim3(256), 0, stream>>>(x, wq, wk, wv, wo, xb, wqkvb, wob);

    // fused QKV projection: [4096, 3072]
    gemm_bt<true><<<dim3(TS / 128, 32), dim3(256), 0, stream>>>(xb, wqkvb, qkv, 4096, TS, 2048);

    // pre-rope K region; transpose V region
    rope_k<<<dim3(4096), dim3(256), 0, stream>>>(qkv, fc);
    transpose_v<<<dim3(Ln / 64, KVn, Bn), dim3(256), 0, stream>>>(qkv, vtb);

    // barrier-free attention
    attn_kernel<<<dim3(128, KVn, Bn), dim3(64), 0, stream>>>(qkv, vtb, fc, ao);

    gemm_bt<false><<<dim3(16, 32), dim3(256), 0, stream>>>(ao, wob, out, 4096, 2048, 2048);
}

// Round 8
// 304.096 us; speedup vs baseline: 1.3930x; 1.3930x over previous
//
#include <hip/hip_runtime.h>
#include <stdint.h>

typedef __bf16 bf16;
typedef __attribute__((ext_vector_type(8))) __bf16 bf16x8;
typedef __attribute__((ext_vector_type(4))) __bf16 bf16x4;
typedef __attribute__((ext_vector_type(4))) short short4v;
typedef __attribute__((ext_vector_type(4))) float f32x4;

static constexpr int Bn = 2, Ln = 2048, DIMn = 2048, Hn = 32, KVn = 8, HDn = 64;
static constexpr int TS = 3072;  // fused qkv token stride (2048 q + 512 k + 512 v)

#if defined(__has_builtin)
#if __has_builtin(__builtin_amdgcn_exp2f)
#define EXP2(x) __builtin_amdgcn_exp2f(x)
#endif
#endif
#ifndef EXP2
#define EXP2(x) exp2f(x)
#endif

#define TO_LDS(p) ((__attribute__((address_space(3))) uint32_t*)(uintptr_t)(p))
#define TO_GLB(p) ((const __attribute__((address_space(1))) uint32_t*)(uintptr_t)(p))

// ---------------- fused cast fp32 -> bf16 for all 5 inputs ----------------
__global__ void cast_all(const float* __restrict__ x, const float* __restrict__ wq,
                         const float* __restrict__ wk, const float* __restrict__ wv,
                         const float* __restrict__ wo, bf16* __restrict__ xb,
                         bf16* __restrict__ wqkvb, bf16* __restrict__ wob) {
    size_t i = (size_t)(blockIdx.x * blockDim.x + threadIdx.x) * 4;
    const float* src;
    bf16* dst;
    if (i < 8388608) {
        src = x + i; dst = xb + i;
    } else if (i < 8388608 + 6291456) {
        size_t j = i - 8388608;
        dst = wqkvb + j;
        if (j < 4194304)      src = wq + j;
        else if (j < 5242880) src = wk + (j - 4194304);
        else                  src = wv + (j - 5242880);
    } else {
        size_t j = i - 14680064;
        src = wo + j; dst = wob + j;
    }
    float4 v = *(const float4*)src;
    bf16 o[4] = {(bf16)v.x, (bf16)v.y, (bf16)v.z, (bf16)v.w};
    *(uint64_t*)dst = *(uint64_t*)o;
}

// ---------------- RoPE in-place on K region of qkv (cols 2048..2559) ----------------
__global__ void rope_k(bf16* __restrict__ qkv, const float* __restrict__ fc) {
    int idx = blockIdx.x * blockDim.x + threadIdx.x;   // T * 8 * 32 = 1,048,576
    int i   = idx & 31;
    int kvh = (idx >> 5) & 7;
    int bl  = idx >> 8;
    int l   = bl & (Ln - 1);
    size_t base = (size_t)bl * TS + 2048 + kvh * 64 + 2 * i;
    float cr = fc[l * 32 + i];
    float sr = fc[65536 + l * 32 + i];
    float x0 = (float)qkv[base], x1 = (float)qkv[base + 1];
    qkv[base]     = (bf16)(x0 * cr - x1 * sr);
    qkv[base + 1] = (bf16)(x0 * sr + x1 * cr);
}

// ---------------- GEMM: C[M,N] = A[M,K] * B[N,K]^T  (bf16 in, fp32 acc) ----------------
template <bool OUT_BF16>
__global__ __launch_bounds__(256) void gemm_bt(const bf16* __restrict__ A,
                                               const bf16* __restrict__ Bm,
                                               void* __restrict__ C,
                                               int M, int N, int K) {
    __shared__ bf16 sA[128 * 32];
    __shared__ bf16 sB[128 * 32];
    const int t    = threadIdx.x;
    const int wave = t >> 6, lane = t & 63;
    const int q4 = lane >> 4, l16 = lane & 15;
    const int bm = blockIdx.y * 128, bn = blockIdx.x * 128;
    const int wm = (wave >> 1) * 64, wn = (wave & 1) * 64;

    f32x4 acc[4][4] = {};

    const int srow = wave * 16 + (lane >> 2);
    const int scol = (lane & 3) * 8;
    const bf16* pa = A + (size_t)(bm + srow) * K + scol;
    const bf16* pb = Bm + (size_t)(bn + srow) * K + scol;
    bf16* la = &sA[wave * 16 * 32];
    bf16* lb = &sB[wave * 16 * 32];

    for (int k0 = 0; k0 < K; k0 += 32) {
#pragma unroll
        for (int p = 0; p < 2; ++p) {
            __builtin_amdgcn_global_load_lds(TO_GLB(pa + (size_t)p * 64 * K),
                                             TO_LDS(la + p * 64 * 32), 16, 0, 0);
            __builtin_amdgcn_global_load_lds(TO_GLB(pb + (size_t)p * 64 * K),
                                             TO_LDS(lb + p * 64 * 32), 16, 0, 0);
        }
        pa += 32; pb += 32;
        __syncthreads();
        bf16x8 af[4], bfr[4];
#pragma unroll
        for (int i = 0; i < 4; ++i) {
            af[i]  = *(const bf16x8*)(&sA[(wm + i * 16 + l16) * 32 + q4 * 8]);
            bfr[i] = *(const bf16x8*)(&sB[(wn + i * 16 + l16) * 32 + q4 * 8]);
        }
#pragma unroll
        for (int mi = 0; mi < 4; ++mi)
#pragma unroll
            for (int ni = 0; ni < 4; ++ni)
                acc[mi][ni] = __builtin_amdgcn_mfma_f32_16x16x32_bf16(af[mi], bfr[ni],
                                                                      acc[mi][ni], 0, 0, 0);
        __syncthreads();
    }

#pragma unroll
    for (int mi = 0; mi < 4; ++mi)
#pragma unroll
        for (int ni = 0; ni < 4; ++ni)
#pragma unroll
            for (int r = 0; r < 4; ++r) {
                size_t row = bm + wm + mi * 16 + q4 * 4 + r;
                size_t col = bn + wn + ni * 16 + l16;
                if (OUT_BF16)
                    ((bf16*)C)[row * N + col] = (bf16)acc[mi][ni][r];
                else
                    ((float*)C)[row * N + col] = acc[mi][ni][r];
            }
}

// ---------------- flash attention: 4 waves = 2 heads x 2 q-halves, uniform pairs ----------------
// Grid = 512 blocks (16 qt-pairs x 2 head-pairs x 8 kvh x 2 b), 256 threads.
// Wave w: head kvh*4 + hp*2 + (w&1), q rows [(w>>1)*32, +32) of the tile, all 64 keys.
// Each block runs q-tiles (31-pair, pair): uniform 33 tile-iters. launch_bounds(256,2)
// -> no VGPR spill, 2 blocks/CU co-resident (one block's compute hides the other's
// barriers). Static-max softmax in log2 domain (scale*log2e folded into in-register
// Q-RoPE): p = exp2(s-12), l deferred to epilogue. K pre-roped; K/V register-prefetched.
__global__ __launch_bounds__(256, 2) void attn_kernel(const bf16* __restrict__ QKV,
                                                      const float* __restrict__ fc,
                                                      bf16* __restrict__ O) {
    constexpr int LDK = 72;
    __shared__ bf16 sK[64 * LDK];          // [key][hd]
    __shared__ bf16 sV[64 * LDK];          // transposed: [hd][key]
    const int t    = threadIdx.x;
    const int wave = t >> 6, lane = t & 63;
    const int q4 = lane >> 4, l16 = lane & 15;
    const int hidx = wave & 1, qh = wave >> 1;
    const int L = blockIdx.x;
    const int pair = L & 15, hp = (L >> 4) & 1, kvh = (L >> 5) & 7, b = L >> 8;
    const int h = kvh * 4 + hp * 2 + hidx;
    constexpr float SC = 0.125f * 1.44269504088896340736f;

    const bf16* kb = QKV + (size_t)(b * Ln) * TS + 2048 + kvh * 64;
    const bf16* vb = kb + 512;
    // staging maps (256 threads; R4-proven)
    const int krow = t >> 3;               // 0..31 (rows krow, krow+32)
    const int kc8  = (t & 7) * 8;
    const int vkey = t & 63, vhd0 = (t >> 6) * 16;

    for (int half = 0; half < 2; ++half) {
        const int qtile = half == 0 ? 31 - pair : pair;

        // ---- load Q fragments (2 groups of 16 rows), RoPE + scale in-register ----
        bf16x8 qf[2][2];
#pragma unroll
        for (int g2 = 0; g2 < 2; ++g2) {
            int ql = qtile * 64 + (qh * 2 + g2) * 16 + l16;
            const bf16* qp = QKV + (size_t)(b * Ln + ql) * TS + h * 64;
#pragma unroll
            for (int hc = 0; hc < 2; ++hc) {
                bf16x8 raw = *(const bf16x8*)(qp + hc * 32 + q4 * 8);
                float4 c4 = *(const float4*)(fc + ql * 32 + hc * 16 + q4 * 4);
                float4 s4 = *(const float4*)(fc + 65536 + ql * 32 + hc * 16 + q4 * 4);
                bf16x8 o;
#pragma unroll
                for (int m = 0; m < 4; ++m) {
                    float cr = ((const float*)&c4)[m], sr = ((const float*)&s4)[m];
                    float x0 = (float)raw[2 * m], x1 = (float)raw[2 * m + 1];
                    o[2 * m]     = (bf16)((x0 * cr - x1 * sr) * SC);
                    o[2 * m + 1] = (bf16)((x0 * sr + x1 * cr) * SC);
                }
                qf[g2][hc] = o;
            }
        }

        f32x4 o_acc[2][4] = {};
        float l_r[2] = {0.f, 0.f};

        // ---- prefetch tile 0 ----
        bf16x8 kreg[2], vreg[2];
#pragma unroll
        for (int p = 0; p < 2; ++p)
            kreg[p] = *(const bf16x8*)(kb + (size_t)(p * 32 + krow) * TS + kc8);
        {
            const bf16* v0 = vb + (size_t)vkey * TS + vhd0;
            vreg[0] = *(const bf16x8*)(v0);
            vreg[1] = *(const bf16x8*)(v0 + 8);
        }

        for (int kt = 0; kt <= qtile; ++kt) {
            // ---- write staged tile to LDS ----
#pragma unroll
            for (int p = 0; p < 2; ++p)
                *(float4*)(&sK[(p * 32 + krow) * LDK + kc8]) = *(float4*)&kreg[p];
            {
                bf16 vv[16];
                *(bf16x8*)(vv)     = vreg[0];
                *(bf16x8*)(vv + 8) = vreg[1];
#pragma unroll
                for (int j = 0; j < 16; ++j) sV[(vhd0 + j) * LDK + vkey] = vv[j];
            }
            __syncthreads();

            // ---- prefetch next tile ----
            if (kt < qtile) {
#pragma unroll
                for (int p = 0; p < 2; ++p)
                    kreg[p] = *(const bf16x8*)(kb + (size_t)((kt + 1) * 64 + p * 32 + krow) * TS + kc8);
                const bf16* v0 = vb + (size_t)((kt + 1) * 64 + vkey) * TS + vhd0;
                vreg[0] = *(const bf16x8*)(v0);
                vreg[1] = *(const bf16x8*)(v0 + 8);
            }

            // ---- fragments (shared across both q-groups) ----
            bf16x8 kf[4][2];
#pragma unroll
            for (int c = 0; c < 4; ++c)
#pragma unroll
                for (int hc = 0; hc < 2; ++hc)
                    kf[c][hc] = *(const bf16x8*)(&sK[(c * 16 + l16) * LDK + hc * 32 + q4 * 8]);
            short4v vf[4][4];
#pragma unroll
            for (int nc = 0; nc < 4; ++nc)
#pragma unroll
                for (int c = 0; c < 4; ++c)
                    vf[nc][c] = *(const short4v*)(&sV[(nc * 16 + l16) * LDK + c * 16 + q4 * 4]);

            const bool diag = (kt == qtile);
#pragma unroll
            for (int g2 = 0; g2 < 2; ++g2) {
                f32x4 s[4];
#pragma unroll
                for (int c = 0; c < 4; ++c) {
                    f32x4 a = {};
                    a = __builtin_amdgcn_mfma_f32_16x16x32_bf16(kf[c][0], qf[g2][0], a, 0, 0, 0);
                    a = __builtin_amdgcn_mfma_f32_16x16x32_bf16(kf[c][1], qf[g2][1], a, 0, 0, 0);
                    s[c] = a;
                }
                int qrow = qtile * 64 + (qh * 2 + g2) * 16 + l16;
                float lsum = 0.f;
                short4v pb4[4];
#pragma unroll
                for (int c = 0; c < 4; ++c)
#pragma unroll
                    for (int r = 0; r < 4; ++r) {
                        float p = EXP2(s[c][r] - 12.f);
                        if (diag && (kt * 64 + c * 16 + q4 * 4 + r > qrow)) p = 0.f;
                        lsum += p;
                        bf16 ph = (bf16)p;
                        pb4[c][r] = *(const short*)&ph;
                    }
                l_r[g2] += lsum;
#pragma unroll
                for (int nc = 0; nc < 4; ++nc)
#pragma unroll
                    for (int c = 0; c < 4; ++c)
                        o_acc[g2][nc] = __builtin_amdgcn_mfma_f32_16x16x16bf16_1k(
                            vf[nc][c], pb4[c], o_acc[g2][nc], 0, 0, 0);
            }
            __syncthreads();
        }

        // ---- epilogue: reduce l across q4 sub-lanes, normalize, store ----
#pragma unroll
        for (int g2 = 0; g2 < 2; ++g2) {
            float l = l_r[g2];
            l += __shfl_xor(l, 16, 64);
            l += __shfl_xor(l, 32, 64);
            float inv = 1.f / l;
            int qrow = qtile * 64 + (qh * 2 + g2) * 16 + l16;
            bf16* op = O + (size_t)(b * Ln + qrow) * (Hn * HDn) + h * 64;
#pragma unroll
            for (int nc = 0; nc < 4; ++nc) {
                bf16x4 o;
#pragma unroll
                for (int r = 0; r < 4; ++r) o[r] = (bf16)(o_acc[g2][nc][r] * inv);
                *(bf16x4*)(op + nc * 16 + q4 * 4) = o;
            }
        }
    }
}

// ---------------- launch ----------------
extern "C" void kernel_launch(void* const* d_in, const int* in_sizes, int n_in,
                              void* d_out, int out_size, void* d_ws, size_t ws_size,
                              hipStream_t stream) {
    const float* x  = (const float*)d_in[0];
    const float* fc = (const float*)d_in[1];
    const float* wq = (const float*)d_in[2];
    const float* wk = (const float*)d_in[3];
    const float* wv = (const float*)d_in[4];
    const float* wo = (const float*)d_in[5];
    float* out = (float*)d_out;

    const size_t T = (size_t)Bn * Ln;  // 4096 tokens
    char* p = (char*)d_ws;
    bf16* xb    = (bf16*)p; p += T * DIMn * 2;
    bf16* wqkvb = (bf16*)p; p += (size_t)TS * DIMn * 2;
    bf16* wob   = (bf16*)p; p += (size_t)DIMn * Hn * HDn * 2;
    bf16* qkv   = (bf16*)p; p += T * TS * 2;
    bf16* ao    = (bf16*)p; p += T * Hn * HDn * 2;

    cast_all<<<dim3(18432), dim3(256), 0, stream>>>(x, wq, wk, wv, wo, xb, wqkvb, wob);

    // fused QKV projection: [4096, 3072]
    gemm_bt<true><<<dim3(TS / 128, 32), dim3(256), 0, stream>>>(xb, wqkvb, qkv, 4096, TS, 2048);

    // pre-rope K region (Q roped in-register inside attn)
    rope_k<<<dim3(4096), dim3(256), 0, stream>>>(qkv, fc);

    // attention: 512 uniform blocks, 4 waves each, 2 blocks/CU
    attn_kernel<<<dim3(512), dim3(256), 0, stream>>>(qkv, fc, ao);

    gemm_bt<false><<<dim3(16, 32), dim3(256), 0, stream>>>(ao, wob, out, 4096, 2048, 2048);
}